// Round 7
// baseline (988.453 us; speedup 1.0000x reference)
//
#include <hip/hip_runtime.h>

#define S_LEN 2048
#define D_DIM 1024
#define H_DIM 4096
#define V_DIM 32000
#define B_SZ  4

typedef float  f32x4  __attribute__((ext_vector_type(4)));
typedef __bf16 bf16x8 __attribute__((ext_vector_type(8)));

__device__ __forceinline__ ushort f2bf(float f) {
    union { float f; unsigned u; } v; v.f = f;
    unsigned r = v.u + 0x7fffu + ((v.u >> 16) & 1u);
    return (ushort)(r >> 16);
}

// ---------------------------------------------------------------------------
// Weight transpose + fp32->bf16 convert: in fp32 [R][C] -> out bf16 [C][R]
// ---------------------------------------------------------------------------
__global__ void bt_wtranspose(const float* __restrict__ in, ushort* __restrict__ out,
                              int R, int C) {
    __shared__ ushort s[64][65];
    int r0 = blockIdx.y * 64, c0 = blockIdx.x * 64;
    int t = threadIdx.x;
    int lr = t >> 2, lc4 = (t & 3) * 16;
    const float* src = in + (size_t)(r0 + lr) * C + c0 + lc4;
#pragma unroll
    for (int j = 0; j < 4; ++j) {
        float4 v = ((const float4*)src)[j];
        s[lr][lc4 + 4 * j + 0] = f2bf(v.x);
        s[lr][lc4 + 4 * j + 1] = f2bf(v.y);
        s[lr][lc4 + 4 * j + 2] = f2bf(v.z);
        s[lr][lc4 + 4 * j + 3] = f2bf(v.w);
    }
    __syncthreads();
    int oc = t >> 2, orr = (t & 3) * 16;
    ushort tmp[16] __attribute__((aligned(16)));
#pragma unroll
    for (int j = 0; j < 16; ++j) tmp[j] = s[orr + j][oc];
    ushort* dst = out + (size_t)(c0 + oc) * R + r0 + orr;
    *(uint4*)dst        = *(uint4*)tmp;
    *(uint4*)(dst + 8)  = *(uint4*)(tmp + 8);
}

// ---------------------------------------------------------------------------
// bf16 transpose: in [R][C] -> out [C][R]
// ---------------------------------------------------------------------------
__global__ void bt_transpose(const ushort* __restrict__ in, ushort* __restrict__ out,
                             int R, int C) {
    __shared__ ushort s[64][65];
    int r0 = blockIdx.y * 64, c0 = blockIdx.x * 64;
    int t = threadIdx.x;
    int lr = t >> 2, lc = (t & 3) * 16;
    const ushort* src = in + (size_t)(r0 + lr) * C + c0 + lc;
    uint4 v0 = ((const uint4*)src)[0];
    uint4 v1 = ((const uint4*)src)[1];
    ushort tin[16] __attribute__((aligned(16)));
    *(uint4*)tin = v0; *(uint4*)(tin + 8) = v1;
#pragma unroll
    for (int j = 0; j < 16; ++j) s[lr][lc + j] = tin[j];
    __syncthreads();
    int oc = t >> 2, orr = (t & 3) * 16;
    ushort tmp[16] __attribute__((aligned(16)));
#pragma unroll
    for (int j = 0; j < 16; ++j) tmp[j] = s[orr + j][oc];
    ushort* dst = out + (size_t)(c0 + oc) * R + r0 + orr;
    *(uint4*)dst       = *(uint4*)tmp;
    *(uint4*)(dst + 8) = *(uint4*)(tmp + 8);
}

// ---------------------------------------------------------------------------
// Embedding + positional encoding
// ---------------------------------------------------------------------------
__global__ void bt_embed(const int* __restrict__ tokens, const float* __restrict__ emb,
                         const float* __restrict__ pe, float* __restrict__ h,
                         ushort* __restrict__ hbf) {
    int row = blockIdx.x;
    int s   = row & (S_LEN - 1);
    int tok = tokens[row];
    int t   = threadIdx.x;
    float4 v = ((const float4*)(emb + (size_t)tok * D_DIM))[t];
    float4 p = ((const float4*)(pe + (size_t)s * D_DIM))[t];
    v.x += p.x; v.y += p.y; v.z += p.z; v.w += p.w;
    ((float4*)(h + (size_t)row * D_DIM))[t] = v;
    uint2 pk;
    pk.x = (unsigned)f2bf(v.x) | ((unsigned)f2bf(v.y) << 16);
    pk.y = (unsigned)f2bf(v.z) | ((unsigned)f2bf(v.w) << 16);
    ((uint2*)(hbf + (size_t)row * D_DIM))[t] = pk;
}

// ---------------------------------------------------------------------------
// Ring-4 K-split GEMM with cross-phase register ping-pong.
// C[m][n] = sum_k A[m][k]*B[n][k]. Every wave owns a 16*MR x 16*NR output
// (acc[8][4] = 128x64 in both configs). Per K=32 half-step phase:
//   vmcnt(G); s_barrier; STAGE(hs+3); read B(hs); read A(hs+1)->other set;
//   MFMA cluster on current set.
// A-frag reads are issued one phase ahead (latency hidden under MFMA);
// compiler inserts fine-grained lgkmcnt (no manual fences, no sched_barrier).
// ---------------------------------------------------------------------------
#define EPI_F32  0
#define EPI_BF16 1
#define EPI_RELU 2
#define EPI_RES  3

#define VMWAIT(N) asm volatile("s_waitcnt vmcnt(%0)" :: "n"(N) : "memory")
#define SBAR()    __builtin_amdgcn_s_barrier()
#define MEMPIN()  asm volatile("" ::: "memory")
#define AS1 __attribute__((address_space(1)))
#define AS3 __attribute__((address_space(3)))

template <int BM, int BN, int NW, int WCc, int EPI, bool CSKIP, bool KLIM, int SWZ>
__global__ __launch_bounds__(NW * 64, (NW == 8 ? 2 : 1))
void bt_gemm(const ushort* __restrict__ A, const ushort* __restrict__ B,
             float* Cf, ushort* Cb, const float* __restrict__ Res,
             int lda, int ldb, int ldc, int K,
             size_t strideA, size_t strideB, size_t strideC) {
    constexpr int WRr = NW / WCc;
    constexpr int MR  = BM / (16 * WRr);     // 8
    constexpr int NR  = BN / (16 * WCc);     // 4
    constexpr int Ak  = BM / (16 * NW);      // stage loads per thread (A)
    constexpr int Bk  = BN / (16 * NW);
    constexpr int G   = Ak + Bk;
    constexpr int HS  = (BM + BN) * 32;      // ushorts per k-half ring slot

    __shared__ ushort lds[4][HS];

    int bm, bn;
    if (SWZ == 1) {
        int gx = gridDim.x, gy = gridDim.y;
        int id = blockIdx.y * gx + blockIdx.x;
        int xcd = id & 7, slot = id >> 3;
        int bandH = gy >> 3;
        bm = xcd * bandH + (slot % bandH);
        bn = slot / bandH;
    } else if (SWZ == 2) {
        int gx = gridDim.x;
        int id = blockIdx.y * gx + blockIdx.x;
        int xcd = id & 7, slot = id >> 3;
        int bandW = gx >> 3;
        bn = xcd * bandW + (slot % bandW);
        bm = slot / bandW;
    } else { bm = blockIdx.y; bn = blockIdx.x; }

    if (CSKIP && bn * BN >= (bm + 1) * BM) return;

    const int tid  = threadIdx.x;
    const int lane = tid & 63;
    const int wid  = tid >> 6;
    const int wr   = wid / WCc, wc = wid % WCc;
    const int r15  = lane & 15, r4 = lane >> 4;
    const int lr   = lane >> 2;
    const int lsl  = lane & 3;
    const int kswz = (r4 ^ ((r15 >> 1) & 3)) * 8;

    const ushort* Ab = A + strideA * blockIdx.z + (size_t)bm * BM * lda;
    const ushort* Bb = B + strideB * blockIdx.z + (size_t)bn * BN * ldb;

    int NT = K >> 6;
    if (KLIM) { int lim = (bm + 1) * (BM / 64); if (lim < NT) NT = lim; }
    const int NH2 = 2 * NT;

    f32x4 acc[MR][NR];
#pragma unroll
    for (int m = 0; m < MR; ++m)
#pragma unroll
        for (int n = 0; n < NR; ++n) acc[m][n] = (f32x4){0.f, 0.f, 0.f, 0.f};

    bf16x8 aqA[MR], aqB[MR], bq[NR];

#define STAGE(hs)                                                                 \
    {                                                                             \
        const int t_ = (hs) >> 1, b_ = (hs) & 3;                                  \
        const int c_ = ((hs) & 1) * 4 + (lsl ^ ((lr >> 1) & 3));                  \
        _Pragma("unroll")                                                         \
        for (int j = 0; j < Ak; ++j) {                                            \
            int row = (wid + j * NW) * 16 + lr;                                   \
            __builtin_amdgcn_global_load_lds(                                     \
                (const AS1 void*)(Ab + (size_t)t_ * 64 + (size_t)row * lda + c_ * 8), \
                (AS3 void*)(&lds[b_][0] + (wid + j * NW) * 512), 16, 0, 0);       \
        }                                                                         \
        _Pragma("unroll")                                                         \
        for (int j = 0; j < Bk; ++j) {                                            \
            int row = (wid + j * NW) * 16 + lr;                                   \
            __builtin_amdgcn_global_load_lds(                                     \
                (const AS1 void*)(Bb + (size_t)t_ * 64 + (size_t)row * ldb + c_ * 8), \
                (AS3 void*)(&lds[b_][BM * 32] + (wid + j * NW) * 512), 16, 0, 0); \
        }                                                                         \
    }

#define READ_A(hs, dst)                                                           \
    {                                                                             \
        const int b_ = (hs) & 3;                                                  \
        _Pragma("unroll")                                                         \
        for (int m = 0; m < MR; ++m) {                                            \
            int row = wr * (16 * MR) + m * 16 + r15;                              \
            dst[m] = *(const bf16x8*)(&lds[b_][row * 32 + kswz]);                 \
        }                                                                         \
    }

#define READ_B(hs)                                                                \
    {                                                                             \
        const int b_ = (hs) & 3;                                                  \
        _Pragma("unroll")                                                         \
        for (int n = 0; n < NR; ++n) {                                            \
            int col = wc * (16 * NR) + n * 16 + r15;                              \
            bq[n] = *(const bf16x8*)(&lds[b_][BM * 32 + col * 32 + kswz]);        \
        }                                                                         \
    }

#define CLUSTER(aset)                                                             \
    __builtin_amdgcn_s_setprio(1);                                                \
    _Pragma("unroll")                                                             \
    for (int m = 0; m < MR; ++m)                                                  \
        _Pragma("unroll")                                                         \
        for (int n = 0; n < NR; ++n)                                              \
            acc[m][n] = __builtin_amdgcn_mfma_f32_16x16x32_bf16(aset[m], bq[n], acc[m][n], 0, 0, 0); \
    __builtin_amdgcn_s_setprio(0);

    // prologue
    STAGE(0); STAGE(1);
    VMWAIT(G); SBAR(); MEMPIN();         // group 0 landed (all waves)
    STAGE(2);
    READ_A(0, aqA);

    for (int t = 0; t < NT - 1; ++t) {
        const int hs = 2 * t;
        // even phase: compute hs (aqA), prefetch A(hs+1)
        VMWAIT(G); SBAR(); MEMPIN();     // group hs+1 landed
        STAGE(hs + 3);
        READ_B(hs);
        READ_A(hs + 1, aqB);
        CLUSTER(aqA);
        // odd phase: compute hs+1 (aqB), prefetch A(hs+2)
        VMWAIT(G); SBAR(); MEMPIN();     // group hs+2 landed
        if (t < NT - 2) STAGE(hs + 4);
        READ_B(hs + 1);
        READ_A(hs + 2, aqA);
        CLUSTER(aqB);
    }
    // tail: aqA = frags(NH2-2); outstanding = {NH2-1}
    VMWAIT(0); SBAR(); MEMPIN();
    READ_B(NH2 - 2);
    READ_A(NH2 - 1, aqB);
    CLUSTER(aqA);
    READ_B(NH2 - 1);
    CLUSTER(aqB);

    // epilogue: frag row = 4*(lane>>4)+r, col = lane&15
    size_t cz = strideC * blockIdx.z;
    const int rowb = bm * BM + wr * (16 * MR) + r4 * 4;
    const int colb = bn * BN + wc * (16 * NR) + r15;
#pragma unroll
    for (int m = 0; m < MR; ++m) {
#pragma unroll
        for (int r = 0; r < 4; ++r) {
            int row = rowb + m * 16 + r;
            size_t base = cz + (size_t)row * ldc + colb;
#pragma unroll
            for (int n = 0; n < NR; ++n) {
                float v = acc[m][n][r];
                size_t idx = base + n * 16;
                if (EPI == EPI_F32)       Cf[idx] = v;
                else if (EPI == EPI_BF16) Cb[idx] = f2bf(v);
                else if (EPI == EPI_RELU) Cb[idx] = f2bf(fmaxf(v, 0.f));
                else { float o = v + Res[idx]; Cf[idx] = o; Cb[idx] = f2bf(o); }
            }
        }
    }
#undef STAGE
#undef READ_A
#undef READ_B
#undef CLUSTER
}

// ---------------------------------------------------------------------------
// Causal row softmax: scores fp32 [B][S][S] -> probs bf16 (zeros above diag)
// ---------------------------------------------------------------------------
__device__ __forceinline__ float wred_max(float v) {
#pragma unroll
    for (int off = 32; off; off >>= 1) v = fmaxf(v, __shfl_xor(v, off));
    return v;
}
__device__ __forceinline__ float wred_sum(float v) {
#pragma unroll
    for (int off = 32; off; off >>= 1) v += __shfl_xor(v, off);
    return v;
}

__global__ void bt_softmax(const float* __restrict__ scores, ushort* __restrict__ probs) {
    int row = blockIdx.x;
    int s   = row & (S_LEN - 1);
    const float* src = scores + (size_t)row * S_LEN;
    ushort*      dst = probs  + (size_t)row * S_LEN;
    int tid = threadIdx.x;
    int nvalid = s + 1;

    float vals[8];
    float mx = -1e30f;
#pragma unroll
    for (int j = 0; j < 8; ++j) {
        int t = tid + j * 256;
        float v = (t < nvalid) ? src[t] * 0.03125f : -1e30f;
        vals[j] = v;
        mx = fmaxf(mx, v);
    }
    __shared__ float red[4], red2[4];
    mx = wred_max(mx);
    if ((tid & 63) == 0) red[tid >> 6] = mx;
    __syncthreads();
    mx = fmaxf(fmaxf(red[0], red[1]), fmaxf(red[2], red[3]));

    float sum = 0.f, ps[8];
#pragma unroll
    for (int j = 0; j < 8; ++j) {
        float p = exp2f((vals[j] - mx) * 1.44269504f);
        ps[j] = p; sum += p;
    }
    sum = wred_sum(sum);
    if ((tid & 63) == 0) red2[tid >> 6] = sum;
    __syncthreads();
    sum = red2[0] + red2[1] + red2[2] + red2[3];
    float inv = 1.0f / sum;
#pragma unroll
    for (int j = 0; j < 8; ++j) {
        int t = tid + j * 256;
        dst[t] = (t < nvalid) ? f2bf(ps[j] * inv) : (ushort)0;
    }
}

// ---------------------------------------------------------------------------
// Last-token logits
// ---------------------------------------------------------------------------
__global__ void bt_logits(const float* __restrict__ h, const float* __restrict__ wout,
                          float* __restrict__ out) {
    __shared__ float hl[4][128];
    int tid = threadIdx.x;
    int d0 = blockIdx.y * 128;
    if (tid < 128) {
#pragma unroll
        for (int b = 0; b < 4; ++b)
            hl[b][tid] = h[((size_t)b * S_LEN + (S_LEN - 1)) * D_DIM + d0 + tid];
    }
    __syncthreads();
    int v = blockIdx.x * 256 + tid;
    float a0 = 0, a1 = 0, a2 = 0, a3 = 0;
    for (int j = 0; j < 128; ++j) {
        float w = wout[(size_t)(d0 + j) * V_DIM + v];
        a0 += hl[0][j] * w; a1 += hl[1][j] * w;
        a2 += hl[2][j] * w; a3 += hl[3][j] * w;
    }
    atomicAdd(out + v, a0);
    atomicAdd(out + V_DIM + v, a1);
    atomicAdd(out + 2 * V_DIM + v, a2);
    atomicAdd(out + 3 * V_DIM + v, a3);
}

// ---------------------------------------------------------------------------
extern "C" void kernel_launch(void* const* d_in, const int* in_sizes, int n_in,
                              void* d_out, int out_size, void* d_ws, size_t ws_size,
                              hipStream_t stream) {
    const int*   tokens = (const int*)d_in[0];
    const float* emb    = (const float*)d_in[1];
    const float* pe     = (const float*)d_in[2];
    const float* wgt[10];
    for (int i = 0; i < 10; ++i) wgt[i] = (const float*)d_in[3 + i];
    const float* wout = (const float*)d_in[13];

    char* w = (char*)d_ws;
    size_t o = 0;
    auto take = [&](size_t sz) { char* p = w + o; o += (sz + 255) & ~(size_t)255; return p; };

    const size_t DD = (size_t)D_DIM * D_DIM * 2;
    const size_t DH = (size_t)D_DIM * H_DIM * 2;
    size_t wsz[10] = {DD, DD, DD, DH, DH, DD, DD, DD, DH, DH};
    ushort* wT[10];
    for (int i = 0; i < 10; ++i) wT[i] = (ushort*)take(wsz[i]);

    const size_t NROW = (size_t)B_SZ * S_LEN;
    float*  h0     = (float*)take(NROW * D_DIM * 4);
    float*  h1     = (float*)take(NROW * D_DIM * 4);
    ushort* hbf    = (ushort*)take(NROW * D_DIM * 2);
    ushort* hresbf = (ushort*)take(NROW * D_DIM * 2);   // also xv temp (disjoint phases)
    ushort* xkbf   = (ushort*)take(NROW * D_DIM * 2);
    ushort* xvt    = (ushort*)take((size_t)D_DIM * NROW * 2);
    ushort* hattn  = (ushort*)take(NROW * D_DIM * 2);
    char*   G      = take((size_t)B_SZ * S_LEN * S_LEN * 4 + (size_t)B_SZ * S_LEN * S_LEN * 2);
    float*  scores = (float*)G;
    ushort* probs  = (ushort*)(G + (size_t)B_SZ * S_LEN * S_LEN * 4);
    ushort* tbf    = (ushort*)G;   // FFN hidden aliases scores (disjoint phases)

    int wR[10] = {1024, 1024, 1024, 1024, 4096, 1024, 1024, 1024, 1024, 4096};
    int wC[10] = {1024, 1024, 1024, 4096, 1024, 1024, 1024, 1024, 4096, 1024};
    for (int i = 0; i < 10; ++i)
        bt_wtranspose<<<dim3(wC[i] / 64, wR[i] / 64), 256, 0, stream>>>(wgt[i], wT[i], wR[i], wC[i]);

    bt_embed<<<NROW, 256, 0, stream>>>(tokens, emb, pe, h0, hbf);

    auto layer = [&](ushort* wk, ushort* wv2, ushort* wo, ushort* w1, ushort* w2) {
        // xk = h @ wk : M=8192, N=1024  (256x128, 4 waves, full-GPU grid)
        bt_gemm<256, 128, 4, 2, EPI_BF16, false, false, 1><<<dim3(8, 32), 256, 0, stream>>>(
            hbf, wk, nullptr, xkbf, nullptr, D_DIM, D_DIM, D_DIM, D_DIM, 0, 0, 0);
        // xv = h @ wv (into hresbf temp), then transpose to xvt [D][B*S]
        bt_gemm<256, 128, 4, 2, EPI_BF16, false, false, 1><<<dim3(8, 32), 256, 0, stream>>>(
            hbf, wv2, nullptr, hresbf, nullptr, D_DIM, D_DIM, D_DIM, D_DIM, 0, 0, 0);
        bt_transpose<<<dim3(D_DIM / 64, NROW / 64), 256, 0, stream>>>(
            hresbf, xvt, (int)NROW, D_DIM);
        // scores = Q @ K^T per batch (causal tiles only), fp32
        bt_gemm<256, 128, 4, 2, EPI_F32, true, false, 0><<<dim3(16, 8, B_SZ), 256, 0, stream>>>(
            hbf, xkbf, scores, nullptr, nullptr, D_DIM, D_DIM, S_LEN, D_DIM,
            (size_t)S_LEN * D_DIM, (size_t)S_LEN * D_DIM, (size_t)S_LEN * S_LEN);
        bt_softmax<<<NROW, 256, 0, stream>>>(scores, probs);
        // h_attn = probs @ xv (B^T = xv^T), causal K-limit
        bt_gemm<256, 128, 4, 2, EPI_BF16, false, true, 0><<<dim3(8, 8, B_SZ), 256, 0, stream>>>(
            probs, xvt, nullptr, hattn, nullptr, S_LEN, (int)NROW, D_DIM, S_LEN,
            (size_t)S_LEN * S_LEN, (size_t)S_LEN, (size_t)S_LEN * D_DIM);
        // h_res = h + h_attn @ wo
        bt_gemm<256, 128, 4, 2, EPI_RES, false, false, 1><<<dim3(8, 32), 256, 0, stream>>>(
            hattn, wo, h1, hresbf, h0, D_DIM, D_DIM, D_DIM, D_DIM, 0, 0, 0);
        // t = relu(h_res @ w1) : 256x256, 8 waves
        bt_gemm<256, 256, 8, 4, EPI_RELU, false, false, 1><<<dim3(16, 32), 512, 0, stream>>>(
            hresbf, w1, nullptr, tbf, nullptr, D_DIM, D_DIM, H_DIM, D_DIM, 0, 0, 0);
        // h = h_res + t @ w2 : K=4096
        bt_gemm<256, 128, 4, 2, EPI_RES, false, false, 1><<<dim3(8, 32), 256, 0, stream>>>(
            tbf, w2, h0, hbf, h1, H_DIM, H_DIM, D_DIM, H_DIM, 0, 0, 0);
    };
    layer(wT[0], wT[1], wT[2], wT[3], wT[4]);
    layer(wT[5], wT[6], wT[7], wT[8], wT[9]);

    hipMemsetAsync(d_out, 0, (size_t)B_SZ * V_DIM * sizeof(float), stream);
    bt_logits<<<dim3(V_DIM / 256, D_DIM / 128), 256, 0, stream>>>(h0, wout, (float*)d_out);
}

// Round 8
// 915.444 us; speedup vs baseline: 1.0798x; 1.0798x over previous
//
#include <hip/hip_runtime.h>

#define S_LEN 2048
#define D_DIM 1024
#define H_DIM 4096
#define V_DIM 32000
#define B_SZ  4

typedef float  f32x4  __attribute__((ext_vector_type(4)));
typedef __bf16 bf16x8 __attribute__((ext_vector_type(8)));

__device__ __forceinline__ ushort f2bf(float f) {
    union { float f; unsigned u; } v; v.f = f;
    unsigned r = v.u + 0x7fffu + ((v.u >> 16) & 1u);
    return (ushort)(r >> 16);
}

// ---------------------------------------------------------------------------
// Weight transpose + fp32->bf16 convert: in fp32 [R][C] -> out bf16 [C][R]
// ---------------------------------------------------------------------------
__global__ void bt_wtranspose(const float* __restrict__ in, ushort* __restrict__ out,
                              int R, int C) {
    __shared__ ushort s[64][65];
    int r0 = blockIdx.y * 64, c0 = blockIdx.x * 64;
    int t = threadIdx.x;
    int lr = t >> 2, lc4 = (t & 3) * 16;
    const float* src = in + (size_t)(r0 + lr) * C + c0 + lc4;
#pragma unroll
    for (int j = 0; j < 4; ++j) {
        float4 v = ((const float4*)src)[j];
        s[lr][lc4 + 4 * j + 0] = f2bf(v.x);
        s[lr][lc4 + 4 * j + 1] = f2bf(v.y);
        s[lr][lc4 + 4 * j + 2] = f2bf(v.z);
        s[lr][lc4 + 4 * j + 3] = f2bf(v.w);
    }
    __syncthreads();
    int oc = t >> 2, orr = (t & 3) * 16;
    ushort tmp[16] __attribute__((aligned(16)));
#pragma unroll
    for (int j = 0; j < 16; ++j) tmp[j] = s[orr + j][oc];
    ushort* dst = out + (size_t)(c0 + oc) * R + r0 + orr;
    *(uint4*)dst        = *(uint4*)tmp;
    *(uint4*)(dst + 8)  = *(uint4*)(tmp + 8);
}

// ---------------------------------------------------------------------------
// bf16 transpose: in [R][C] -> out [C][R]
// ---------------------------------------------------------------------------
__global__ void bt_transpose(const ushort* __restrict__ in, ushort* __restrict__ out,
                             int R, int C) {
    __shared__ ushort s[64][65];
    int r0 = blockIdx.y * 64, c0 = blockIdx.x * 64;
    int t = threadIdx.x;
    int lr = t >> 2, lc = (t & 3) * 16;
    const ushort* src = in + (size_t)(r0 + lr) * C + c0 + lc;
    uint4 v0 = ((const uint4*)src)[0];
    uint4 v1 = ((const uint4*)src)[1];
    ushort tin[16] __attribute__((aligned(16)));
    *(uint4*)tin = v0; *(uint4*)(tin + 8) = v1;
#pragma unroll
    for (int j = 0; j < 16; ++j) s[lr][lc + j] = tin[j];
    __syncthreads();
    int oc = t >> 2, orr = (t & 3) * 16;
    ushort tmp[16] __attribute__((aligned(16)));
#pragma unroll
    for (int j = 0; j < 16; ++j) tmp[j] = s[orr + j][oc];
    ushort* dst = out + (size_t)(c0 + oc) * R + r0 + orr;
    *(uint4*)dst       = *(uint4*)tmp;
    *(uint4*)(dst + 8) = *(uint4*)(tmp + 8);
}

// ---------------------------------------------------------------------------
// Embedding + positional encoding
// ---------------------------------------------------------------------------
__global__ void bt_embed(const int* __restrict__ tokens, const float* __restrict__ emb,
                         const float* __restrict__ pe, float* __restrict__ h,
                         ushort* __restrict__ hbf) {
    int row = blockIdx.x;
    int s   = row & (S_LEN - 1);
    int tok = tokens[row];
    int t   = threadIdx.x;
    float4 v = ((const float4*)(emb + (size_t)tok * D_DIM))[t];
    float4 p = ((const float4*)(pe + (size_t)s * D_DIM))[t];
    v.x += p.x; v.y += p.y; v.z += p.z; v.w += p.w;
    ((float4*)(h + (size_t)row * D_DIM))[t] = v;
    uint2 pk;
    pk.x = (unsigned)f2bf(v.x) | ((unsigned)f2bf(v.y) << 16);
    pk.y = (unsigned)f2bf(v.z) | ((unsigned)f2bf(v.w) << 16);
    ((uint2*)(hbf + (size_t)row * D_DIM))[t] = pk;
}

// ---------------------------------------------------------------------------
// m201-style fine-phase GEMM. C[m][n] = sum_k A[m][k]*B[n][k].
// Ring-4 of K=32 slots (each: A[BM][32]+B[BN][32], XOR-swizzled chunks).
// Per slot, 2 phases (m-half each):
//   {ds_read A-half + B; stage 2 gload_lds (part of slot s+3);
//    s_barrier; lgkmcnt(0)+sched_barrier(0); setprio(1); MFMA quadrant;
//    setprio(0); [vmcnt(8) at slot end]; s_barrier}
// Counted vmcnt once per slot (8 = 2 slots in flight), drains 4->0 in tail.
// Trailing barrier per phase = WAR fence so stage(s+3) can overwrite slot s-1.
// 2 waves/SIMD everywhere (128^2/4w/64KB -> 2 blk/CU; 256^2/8w/128KB -> 1).
// ---------------------------------------------------------------------------
#define EPI_F32  0
#define EPI_BF16 1
#define EPI_RELU 2
#define EPI_RES  3

#define VMWAIT(N) asm volatile("s_waitcnt vmcnt(%0)" :: "n"(N) : "memory")
#define LGKM0()   asm volatile("s_waitcnt lgkmcnt(0)" ::: "memory")
#define SBAR()    __builtin_amdgcn_s_barrier()
#define SCHED0()  __builtin_amdgcn_sched_barrier(0)
#define AS1 __attribute__((address_space(1)))
#define AS3 __attribute__((address_space(3)))

template <int BM, int BN, int NW, int WCc, int EPI, bool CSKIP, bool KLIM, int SWZ>
__global__ __launch_bounds__(NW * 64, (NW == 8 ? 1 : 2))
void bt_gemm(const ushort* __restrict__ A, const ushort* __restrict__ B,
             float* Cf, ushort* Cb, const float* __restrict__ Res,
             int lda, int ldb, int ldc, int K,
             size_t strideA, size_t strideB, size_t strideC) {
    constexpr int WRr = NW / WCc;            // 2
    constexpr int MR  = BM / (16 * WRr);     // 4 (128) / 8 (256)
    constexpr int NR  = BN / (16 * WCc);     // 4
    constexpr int MH  = MR / 2;              // m-frags per phase
    constexpr int SLOT = (BM + BN) * 32;     // ushorts per K=32 ring slot

    __shared__ ushort lds[4][SLOT];          // 64KB (128^2) / 128KB (256^2)

    int bm, bn;
    if (SWZ == 1) {
        int gx = gridDim.x, gy = gridDim.y;
        int id = blockIdx.y * gx + blockIdx.x;
        int xcd = id & 7, slot = id >> 3;
        int bandH = gy >> 3;
        bm = xcd * bandH + (slot % bandH);
        bn = slot / bandH;
    } else if (SWZ == 2) {
        int gx = gridDim.x;
        int id = blockIdx.y * gx + blockIdx.x;
        int xcd = id & 7, slot = id >> 3;
        int bandW = gx >> 3;
        bn = xcd * bandW + (slot % bandW);
        bm = slot / bandW;
    } else { bm = blockIdx.y; bn = blockIdx.x; }

    if (CSKIP && bn * BN >= (bm + 1) * BM) return;

    const int tid  = threadIdx.x;
    const int lane = tid & 63;
    const int wid  = tid >> 6;
    const int wr   = wid / WCc, wc = wid % WCc;
    const int r15  = lane & 15, r4 = lane >> 4;
    const int lr   = lane >> 2;
    const int lsl  = lane & 3;
    const int kswz = (r4 ^ ((r15 >> 1) & 3)) * 8;

    const ushort* Ab = A + strideA * blockIdx.z + (size_t)bm * BM * lda;
    const ushort* Bb = B + strideB * blockIdx.z + (size_t)bn * BN * ldb;

    int NT = K >> 6;
    if (KLIM) { int lim = (bm + 1) * (BM / 64); if (lim < NT) NT = lim; }
    const int NH2 = 2 * NT;                  // K=32 slots (>= 4 always)

    f32x4 acc[MR][NR];
#pragma unroll
    for (int m = 0; m < MR; ++m)
#pragma unroll
        for (int n = 0; n < NR; ++n) acc[m][n] = (f32x4){0.f, 0.f, 0.f, 0.f};

// stage one part (p = 0/1) of slot s_: 1 A load + 1 B load per thread.
// Global source chunk pre-swizzled; LDS dest linear (both-sides rule m104/m231).
#define STAGE_PART(s_, p_)                                                        \
    {                                                                             \
        const int b_ = (s_) & 3;                                                  \
        const int c_ = lsl ^ ((lr >> 1) & 3);                                     \
        const int rw_ = (wid + (p_) * NW) * 16 + lr;                              \
        __builtin_amdgcn_global_load_lds(                                         \
            (const AS1 void*)(Ab + (size_t)(s_) * 32 + (size_t)rw_ * lda + c_ * 8), \
            (AS3 void*)(&lds[b_][0] + (wid + (p_) * NW) * 512), 16, 0, 0);        \
        __builtin_amdgcn_global_load_lds(                                         \
            (const AS1 void*)(Bb + (size_t)(s_) * 32 + (size_t)rw_ * ldb + c_ * 8), \
            (AS3 void*)(&lds[b_][BM * 32] + (wid + (p_) * NW) * 512), 16, 0, 0);  \
    }

// one phase: m-half mh_ of slot s_; optionally stage part mh_ of slot s_+3.
#define PHASE(s_, mh_, DOSTAGE)                                                   \
    {                                                                             \
        const int b_ = (s_) & 3;                                                  \
        bf16x8 aq[MH], bq[NR];                                                    \
        _Pragma("unroll")                                                         \
        for (int mm = 0; mm < MH; ++mm) {                                         \
            int row = wr * (16 * MR) + ((mh_) * MH + mm) * 16 + r15;              \
            aq[mm] = *(const bf16x8*)(&lds[b_][row * 32 + kswz]);                 \
        }                                                                         \
        _Pragma("unroll")                                                         \
        for (int n = 0; n < NR; ++n) {                                            \
            int col = wc * (16 * NR) + n * 16 + r15;                              \
            bq[n] = *(const bf16x8*)(&lds[b_][BM * 32 + col * 32 + kswz]);        \
        }                                                                         \
        if (DOSTAGE) STAGE_PART((s_) + 3, mh_);                                   \
        SBAR();                                                                   \
        LGKM0(); SCHED0();                                                        \
        __builtin_amdgcn_s_setprio(1);                                            \
        _Pragma("unroll")                                                         \
        for (int mm = 0; mm < MH; ++mm)                                           \
            _Pragma("unroll")                                                     \
            for (int n = 0; n < NR; ++n)                                          \
                acc[(mh_) * MH + mm][n] =                                         \
                    __builtin_amdgcn_mfma_f32_16x16x32_bf16(aq[mm], bq[n],        \
                        acc[(mh_) * MH + mm][n], 0, 0, 0);                        \
        __builtin_amdgcn_s_setprio(0);                                            \
    }

    // prologue: stage slots 0,1,2 (12 loads); slot 0 ready when <=8 outstanding
    STAGE_PART(0, 0); STAGE_PART(0, 1);
    STAGE_PART(1, 0); STAGE_PART(1, 1);
    STAGE_PART(2, 0); STAGE_PART(2, 1);
    VMWAIT(8); SBAR();

    int s = 0;
    for (; s < NH2 - 3; ++s) {               // full-stage slots
        PHASE(s, 0, true);  SBAR();
        PHASE(s, 1, true);  VMWAIT(8); SBAR();   // slot s+1 landed
    }
    // s = NH2-3: no staging; outstanding after = slot NH2-1 only
    PHASE(s, 0, false); SBAR();
    PHASE(s, 1, false); VMWAIT(4); SBAR();
    ++s;
    // s = NH2-2
    PHASE(s, 0, false); SBAR();
    PHASE(s, 1, false); VMWAIT(0); SBAR();
    ++s;
    // s = NH2-1 (last)
    PHASE(s, 0, false); SBAR();
    PHASE(s, 1, false);

    // epilogue: frag row = 4*(lane>>4)+r, col = lane&15
    size_t cz = strideC * blockIdx.z;
    const int rowb = bm * BM + wr * (16 * MR) + r4 * 4;
    const int colb = bn * BN + wc * (16 * NR) + r15;
#pragma unroll
    for (int m = 0; m < MR; ++m) {
#pragma unroll
        for (int r = 0; r < 4; ++r) {
            int row = rowb + m * 16 + r;
            size_t base = cz + (size_t)row * ldc + colb;
#pragma unroll
            for (int n = 0; n < NR; ++n) {
                float v = acc[m][n][r];
                size_t idx = base + n * 16;
                if (EPI == EPI_F32)       Cf[idx] = v;
                else if (EPI == EPI_BF16) Cb[idx] = f2bf(v);
                else if (EPI == EPI_RELU) Cb[idx] = f2bf(fmaxf(v, 0.f));
                else { float o = v + Res[idx]; Cf[idx] = o; Cb[idx] = f2bf(o); }
            }
        }
    }
#undef STAGE_PART
#undef PHASE
}

// ---------------------------------------------------------------------------
// Causal row softmax: scores fp32 [B][S][S] -> probs bf16 (zeros above diag)
// ---------------------------------------------------------------------------
__device__ __forceinline__ float wred_max(float v) {
#pragma unroll
    for (int off = 32; off; off >>= 1) v = fmaxf(v, __shfl_xor(v, off));
    return v;
}
__device__ __forceinline__ float wred_sum(float v) {
#pragma unroll
    for (int off = 32; off; off >>= 1) v += __shfl_xor(v, off);
    return v;
}

__global__ void bt_softmax(const float* __restrict__ scores, ushort* __restrict__ probs) {
    int row = blockIdx.x;
    int s   = row & (S_LEN - 1);
    const float* src = scores + (size_t)row * S_LEN;
    ushort*      dst = probs  + (size_t)row * S_LEN;
    int tid = threadIdx.x;
    int nvalid = s + 1;

    float vals[8];
    float mx = -1e30f;
#pragma unroll
    for (int j = 0; j < 8; ++j) {
        int t = tid + j * 256;
        float v = (t < nvalid) ? src[t] * 0.03125f : -1e30f;
        vals[j] = v;
        mx = fmaxf(mx, v);
    }
    __shared__ float red[4], red2[4];
    mx = wred_max(mx);
    if ((tid & 63) == 0) red[tid >> 6] = mx;
    __syncthreads();
    mx = fmaxf(fmaxf(red[0], red[1]), fmaxf(red[2], red[3]));

    float sum = 0.f, ps[8];
#pragma unroll
    for (int j = 0; j < 8; ++j) {
        float p = exp2f((vals[j] - mx) * 1.44269504f);
        ps[j] = p; sum += p;
    }
    sum = wred_sum(sum);
    if ((tid & 63) == 0) red2[tid >> 6] = sum;
    __syncthreads();
    sum = red2[0] + red2[1] + red2[2] + red2[3];
    float inv = 1.0f / sum;
#pragma unroll
    for (int j = 0; j < 8; ++j) {
        int t = tid + j * 256;
        dst[t] = (t < nvalid) ? f2bf(ps[j] * inv) : (ushort)0;
    }
}

// ---------------------------------------------------------------------------
// Last-token logits
// ---------------------------------------------------------------------------
__global__ void bt_logits(const float* __restrict__ h, const float* __restrict__ wout,
                          float* __restrict__ out) {
    __shared__ float hl[4][128];
    int tid = threadIdx.x;
    int d0 = blockIdx.y * 128;
    if (tid < 128) {
#pragma unroll
        for (int b = 0; b < 4; ++b)
            hl[b][tid] = h[((size_t)b * S_LEN + (S_LEN - 1)) * D_DIM + d0 + tid];
    }
    __syncthreads();
    int v = blockIdx.x * 256 + tid;
    float a0 = 0, a1 = 0, a2 = 0, a3 = 0;
    for (int j = 0; j < 128; ++j) {
        float w = wout[(size_t)(d0 + j) * V_DIM + v];
        a0 += hl[0][j] * w; a1 += hl[1][j] * w;
        a2 += hl[2][j] * w; a3 += hl[3][j] * w;
    }
    atomicAdd(out + v, a0);
    atomicAdd(out + V_DIM + v, a1);
    atomicAdd(out + 2 * V_DIM + v, a2);
    atomicAdd(out + 3 * V_DIM + v, a3);
}

// ---------------------------------------------------------------------------
extern "C" void kernel_launch(void* const* d_in, const int* in_sizes, int n_in,
                              void* d_out, int out_size, void* d_ws, size_t ws_size,
                              hipStream_t stream) {
    const int*   tokens = (const int*)d_in[0];
    const float* emb    = (const float*)d_in[1];
    const float* pe     = (const float*)d_in[2];
    const float* wgt[10];
    for (int i = 0; i < 10; ++i) wgt[i] = (const float*)d_in[3 + i];
    const float* wout = (const float*)d_in[13];

    char* w = (char*)d_ws;
    size_t o = 0;
    auto take = [&](size_t sz) { char* p = w + o; o += (sz + 255) & ~(size_t)255; return p; };

    const size_t DD = (size_t)D_DIM * D_DIM * 2;
    const size_t DH = (size_t)D_DIM * H_DIM * 2;
    size_t wsz[10] = {DD, DD, DD, DH, DH, DD, DD, DD, DH, DH};
    ushort* wT[10];
    for (int i = 0; i < 10; ++i) wT[i] = (ushort*)take(wsz[i]);

    const size_t NROW = (size_t)B_SZ * S_LEN;
    float*  h0     = (float*)take(NROW * D_DIM * 4);
    float*  h1     = (float*)take(NROW * D_DIM * 4);
    ushort* hbf    = (ushort*)take(NROW * D_DIM * 2);
    ushort* hresbf = (ushort*)take(NROW * D_DIM * 2);   // also xv temp (disjoint phases)
    ushort* xkbf   = (ushort*)take(NROW * D_DIM * 2);
    ushort* xvt    = (ushort*)take((size_t)D_DIM * NROW * 2);
    ushort* hattn  = (ushort*)take(NROW * D_DIM * 2);
    char*   G      = take((size_t)B_SZ * S_LEN * S_LEN * 4 + (size_t)B_SZ * S_LEN * S_LEN * 2);
    float*  scores = (float*)G;
    ushort* probs  = (ushort*)(G + (size_t)B_SZ * S_LEN * S_LEN * 4);
    ushort* tbf    = (ushort*)G;   // FFN hidden aliases scores (disjoint phases)

    int wR[10] = {1024, 1024, 1024, 1024, 4096, 1024, 1024, 1024, 1024, 4096};
    int wC[10] = {1024, 1024, 1024, 4096, 1024, 1024, 1024, 1024, 4096, 1024};
    for (int i = 0; i < 10; ++i)
        bt_wtranspose<<<dim3(wC[i] / 64, wR[i] / 64), 256, 0, stream>>>(wgt[i], wT[i], wR[i], wC[i]);

    bt_embed<<<NROW, 256, 0, stream>>>(tokens, emb, pe, h0, hbf);

    auto layer = [&](ushort* wk, ushort* wv2, ushort* wo, ushort* w1, ushort* w2) {
        // xk = h @ wk : M=8192, N=1024
        bt_gemm<128, 128, 4, 2, EPI_BF16, false, false, 1><<<dim3(8, 64), 256, 0, stream>>>(
            hbf, wk, nullptr, xkbf, nullptr, D_DIM, D_DIM, D_DIM, D_DIM, 0, 0, 0);
        // xv = h @ wv (into hresbf temp), then transpose to xvt [D][B*S]
        bt_gemm<128, 128, 4, 2, EPI_BF16, false, false, 1><<<dim3(8, 64), 256, 0, stream>>>(
            hbf, wv2, nullptr, hresbf, nullptr, D_DIM, D_DIM, D_DIM, D_DIM, 0, 0, 0);
        bt_transpose<<<dim3(D_DIM / 64, NROW / 64), 256, 0, stream>>>(
            hresbf, xvt, (int)NROW, D_DIM);
        // scores = Q @ K^T per batch (causal tiles only), fp32
        bt_gemm<128, 128, 4, 2, EPI_F32, true, false, 0><<<dim3(16, 16, B_SZ), 256, 0, stream>>>(
            hbf, xkbf, scores, nullptr, nullptr, D_DIM, D_DIM, S_LEN, D_DIM,
            (size_t)S_LEN * D_DIM, (size_t)S_LEN * D_DIM, (size_t)S_LEN * S_LEN);
        bt_softmax<<<NROW, 256, 0, stream>>>(scores, probs);
        // h_attn = probs @ xv (B^T = xv^T), causal K-limit
        bt_gemm<128, 128, 4, 2, EPI_BF16, false, true, 0><<<dim3(8, 16, B_SZ), 256, 0, stream>>>(
            probs, xvt, nullptr, hattn, nullptr, S_LEN, (int)NROW, D_DIM, S_LEN,
            (size_t)S_LEN * S_LEN, (size_t)S_LEN, (size_t)S_LEN * D_DIM);
        // h_res = h + h_attn @ wo
        bt_gemm<128, 128, 4, 2, EPI_RES, false, false, 1><<<dim3(8, 64), 256, 0, stream>>>(
            hattn, wo, h1, hresbf, h0, D_DIM, D_DIM, D_DIM, D_DIM, 0, 0, 0);
        // t = relu(h_res @ w1) : 256x256, 8 waves (m201 geometry)
        bt_gemm<256, 256, 8, 4, EPI_RELU, false, false, 1><<<dim3(16, 32), 512, 0, stream>>>(
            hresbf, w1, nullptr, tbf, nullptr, D_DIM, D_DIM, H_DIM, D_DIM, 0, 0, 0);
        // h = h_res + t @ w2 : K=4096
        bt_gemm<128, 128, 4, 2, EPI_RES, false, false, 1><<<dim3(8, 64), 256, 0, stream>>>(
            tbf, w2, h0, hbf, h1, H_DIM, H_DIM, D_DIM, H_DIM, 0, 0, 0);
    };
    layer(wT[0], wT[1], wT[2], wT[3], wT[4]);
    layer(wT[5], wT[6], wT[7], wT[8], wT[9]);

    hipMemsetAsync(d_out, 0, (size_t)B_SZ * V_DIM * sizeof(float), stream);
    bt_logits<<<dim3(V_DIM / 256, D_DIM / 128), 256, 0, stream>>>(h0, wout, (float*)d_out);
}

// Round 9
// 838.432 us; speedup vs baseline: 1.1789x; 1.0919x over previous
//
#include <hip/hip_runtime.h>

#define S_LEN 2048
#define D_DIM 1024
#define H_DIM 4096
#define V_DIM 32000
#define B_SZ  4

typedef float  f32x4  __attribute__((ext_vector_type(4)));
typedef __bf16 bf16x8 __attribute__((ext_vector_type(8)));

__device__ __forceinline__ ushort f2bf(float f) {
    union { float f; unsigned u; } v; v.f = f;
    unsigned r = v.u + 0x7fffu + ((v.u >> 16) & 1u);
    return (ushort)(r >> 16);
}

// ---------------------------------------------------------------------------
// Weight transpose + fp32->bf16 convert: in fp32 [R][C] -> out bf16 [C][R]
// ---------------------------------------------------------------------------
__global__ void bt_wtranspose(const float* __restrict__ in, ushort* __restrict__ out,
                              int R, int C) {
    __shared__ ushort s[64][65];
    int r0 = blockIdx.y * 64, c0 = blockIdx.x * 64;
    int t = threadIdx.x;
    int lr = t >> 2, lc4 = (t & 3) * 16;
    const float* src = in + (size_t)(r0 + lr) * C + c0 + lc4;
#pragma unroll
    for (int j = 0; j < 4; ++j) {
        float4 v = ((const float4*)src)[j];
        s[lr][lc4 + 4 * j + 0] = f2bf(v.x);
        s[lr][lc4 + 4 * j + 1] = f2bf(v.y);
        s[lr][lc4 + 4 * j + 2] = f2bf(v.z);
        s[lr][lc4 + 4 * j + 3] = f2bf(v.w);
    }
    __syncthreads();
    int oc = t >> 2, orr = (t & 3) * 16;
    ushort tmp[16] __attribute__((aligned(16)));
#pragma unroll
    for (int j = 0; j < 16; ++j) tmp[j] = s[orr + j][oc];
    ushort* dst = out + (size_t)(c0 + oc) * R + r0 + orr;
    *(uint4*)dst        = *(uint4*)tmp;
    *(uint4*)(dst + 8)  = *(uint4*)(tmp + 8);
}

// ---------------------------------------------------------------------------
// bf16 transpose of a column slice: out[c][r] = in[r][coff + c]
// in ld = ldin; out ld = R.
// ---------------------------------------------------------------------------
__global__ void bt_transpose(const ushort* __restrict__ in, ushort* __restrict__ out,
                             int R, int ldin, int coff) {
    __shared__ ushort s[64][65];
    int r0 = blockIdx.y * 64, c0 = blockIdx.x * 64;
    int t = threadIdx.x;
    int lr = t >> 2, lc = (t & 3) * 16;
    const ushort* src = in + (size_t)(r0 + lr) * ldin + coff + c0 + lc;
    uint4 v0 = ((const uint4*)src)[0];
    uint4 v1 = ((const uint4*)src)[1];
    ushort tin[16] __attribute__((aligned(16)));
    *(uint4*)tin = v0; *(uint4*)(tin + 8) = v1;
#pragma unroll
    for (int j = 0; j < 16; ++j) s[lr][lc + j] = tin[j];
    __syncthreads();
    int oc = t >> 2, orr = (t & 3) * 16;
    ushort tmp[16] __attribute__((aligned(16)));
#pragma unroll
    for (int j = 0; j < 16; ++j) tmp[j] = s[orr + j][oc];
    ushort* dst = out + (size_t)(c0 + oc) * R + r0 + orr;
    *(uint4*)dst       = *(uint4*)tmp;
    *(uint4*)(dst + 8) = *(uint4*)(tmp + 8);
}

// ---------------------------------------------------------------------------
// Embedding + positional encoding
// ---------------------------------------------------------------------------
__global__ void bt_embed(const int* __restrict__ tokens, const float* __restrict__ emb,
                         const float* __restrict__ pe, float* __restrict__ h,
                         ushort* __restrict__ hbf) {
    int row = blockIdx.x;
    int s   = row & (S_LEN - 1);
    int tok = tokens[row];
    int t   = threadIdx.x;
    float4 v = ((const float4*)(emb + (size_t)tok * D_DIM))[t];
    float4 p = ((const float4*)(pe + (size_t)s * D_DIM))[t];
    v.x += p.x; v.y += p.y; v.z += p.z; v.w += p.w;
    ((float4*)(h + (size_t)row * D_DIM))[t] = v;
    uint2 pk;
    pk.x = (unsigned)f2bf(v.x) | ((unsigned)f2bf(v.y) << 16);
    pk.y = (unsigned)f2bf(v.z) | ((unsigned)f2bf(v.w) << 16);
    ((uint2*)(hbf + (size_t)row * D_DIM))[t] = pk;
}

// ---------------------------------------------------------------------------
// 8-wave big-tile GEMM (m201 geometry). C[m][n] = sum_k A[m][k]*B[n][k].
// 512 threads, 8 waves arranged WRr x WCc; per-wave tile 16MR x 16NR
// (256^2: 128x64, 67% LDS-feed ceiling; 256x128: 64x64, 49%).
// Ring-4 of K=32 slots; per slot 2 phases (m-halves); B-frags read ONCE per
// slot (held in regs across phases); counted vmcnt never 0 in main loop.
// 8-wave blocks keep 2 waves/SIMD even at 1 block/CU (R7 lesson).
// ---------------------------------------------------------------------------
#define EPI_F32  0
#define EPI_BF16 1
#define EPI_RELU 2
#define EPI_RES  3

#define VMWAIT(N) asm volatile("s_waitcnt vmcnt(%0)" :: "n"(N) : "memory")
#define LGKM0()   asm volatile("s_waitcnt lgkmcnt(0)" ::: "memory")
#define SBAR()    __builtin_amdgcn_s_barrier()
#define SCHED0()  __builtin_amdgcn_sched_barrier(0)
#define AS1 __attribute__((address_space(1)))
#define AS3 __attribute__((address_space(3)))

template <int BM, int BN, int WRr, int WCc, int EPI, bool CSKIP, bool KLIM, int SWZ>
__global__ __launch_bounds__(512, 2)
void bt_gemm(const ushort* __restrict__ A, const ushort* __restrict__ B,
             float* Cf, ushort* Cb, const float* __restrict__ Res,
             int lda, int ldb, int ldc, int K,
             size_t strideA, size_t strideB, size_t strideC) {
    constexpr int MR  = BM / (16 * WRr);     // 8 (256^2) / 4 (256x128)
    constexpr int NR  = BN / (16 * WCc);     // 4
    constexpr int MH  = MR / 2;
    constexpr int APARTS = BM / 128;         // 2
    constexpr int BPARTS = BN / 128;         // 2 or 1
    constexpr int LPS = APARTS + BPARTS;     // loads/slot/thread: 4 or 3
    constexpr int SLOT = (BM + BN) * 32;     // ushorts per K=32 ring slot

    __shared__ ushort lds[4][SLOT];          // 128KB / 96KB

    int bm, bn;
    if (SWZ == 1) {
        int gx = gridDim.x, gy = gridDim.y;
        int id = blockIdx.y * gx + blockIdx.x;
        int xcd = id & 7, slot = id >> 3;
        int bandH = gy >> 3;
        bm = xcd * bandH + (slot % bandH);
        bn = slot / bandH;
    } else { bm = blockIdx.y; bn = blockIdx.x; }

    if (CSKIP && bn * BN >= (bm + 1) * BM) return;

    const int tid  = threadIdx.x;
    const int lane = tid & 63;
    const int wid  = tid >> 6;               // 8 waves
    const int wr   = wid / WCc, wc = wid % WCc;
    const int r15  = lane & 15, r4 = lane >> 4;
    const int lr   = lane >> 2;
    const int lsl  = lane & 3;
    const int kswz = (r4 ^ ((r15 >> 1) & 3)) * 8;

    const ushort* Ab = A + strideA * blockIdx.z + (size_t)bm * BM * lda;
    const ushort* Bb = B + strideB * blockIdx.z + (size_t)bn * BN * ldb;

    int NT = K >> 6;
    if (KLIM) { int lim = (bm + 1) * (BM / 64); if (lim < NT) NT = lim; }
    const int NH2 = 2 * NT;                  // K=32 slots (>= 8 here)

    f32x4 acc[MR][NR];
#pragma unroll
    for (int m = 0; m < MR; ++m)
#pragma unroll
        for (int n = 0; n < NR; ++n) acc[m][n] = (f32x4){0.f, 0.f, 0.f, 0.f};

    bf16x8 bq[NR];                            // live across both phases of a slot

// stage part p_ of slot s_ (rows (wid + p_*8)*16+lr): 1 A load; B only while
// rows < BN (compile-time folds for BN=128).
#define STAGE_PART(s_, p_)                                                        \
    {                                                                             \
        const int b_ = (s_) & 3;                                                  \
        const int c_ = lsl ^ ((lr >> 1) & 3);                                     \
        const int rw_ = (wid + (p_) * 8) * 16 + lr;                               \
        __builtin_amdgcn_global_load_lds(                                         \
            (const AS1 void*)(Ab + (size_t)(s_) * 32 + (size_t)rw_ * lda + c_ * 8), \
            (AS3 void*)(&lds[b_][0] + (wid + (p_) * 8) * 512), 16, 0, 0);         \
        if (BPARTS == 2 || (p_) == 0)                                             \
            __builtin_amdgcn_global_load_lds(                                     \
                (const AS1 void*)(Bb + (size_t)(s_) * 32 + (size_t)rw_ * ldb + c_ * 8), \
                (AS3 void*)(&lds[b_][BM * 32] + (wid + (p_) * 8) * 512), 16, 0, 0); \
    }

// phase mh_ of slot s_: phase 0 also reads all B-frags; optional staging.
#define PHASE(s_, mh_, DOSTAGE)                                                   \
    {                                                                             \
        const int b_ = (s_) & 3;                                                  \
        bf16x8 aq[MH];                                                            \
        if ((mh_) == 0) {                                                         \
            _Pragma("unroll")                                                     \
            for (int n = 0; n < NR; ++n) {                                        \
                int col = wc * (16 * NR) + n * 16 + r15;                          \
                bq[n] = *(const bf16x8*)(&lds[b_][BM * 32 + col * 32 + kswz]);    \
            }                                                                     \
        }                                                                         \
        _Pragma("unroll")                                                         \
        for (int mm = 0; mm < MH; ++mm) {                                         \
            int row = wr * (16 * MR) + ((mh_) * MH + mm) * 16 + r15;              \
            aq[mm] = *(const bf16x8*)(&lds[b_][row * 32 + kswz]);                 \
        }                                                                         \
        if (DOSTAGE) STAGE_PART((s_) + 3, mh_);                                   \
        SBAR();                                                                   \
        LGKM0(); SCHED0();                                                        \
        __builtin_amdgcn_s_setprio(1);                                            \
        _Pragma("unroll")                                                         \
        for (int mm = 0; mm < MH; ++mm)                                           \
            _Pragma("unroll")                                                     \
            for (int n = 0; n < NR; ++n)                                          \
                acc[(mh_) * MH + mm][n] =                                         \
                    __builtin_amdgcn_mfma_f32_16x16x32_bf16(aq[mm], bq[n],        \
                        acc[(mh_) * MH + mm][n], 0, 0, 0);                        \
        __builtin_amdgcn_s_setprio(0);                                            \
    }

    // prologue: stage slots 0,1,2
    STAGE_PART(0, 0); STAGE_PART(0, 1);
    STAGE_PART(1, 0); STAGE_PART(1, 1);
    STAGE_PART(2, 0); STAGE_PART(2, 1);
    VMWAIT(2 * LPS); SBAR();                 // slot 0 landed

    int s = 0;
    for (; s < NH2 - 3; ++s) {
        PHASE(s, 0, true);  SBAR();
        PHASE(s, 1, true);  VMWAIT(2 * LPS); SBAR();   // slot s+1 landed
    }
    PHASE(s, 0, false); SBAR();
    PHASE(s, 1, false); VMWAIT(LPS); SBAR();
    ++s;
    PHASE(s, 0, false); SBAR();
    PHASE(s, 1, false); VMWAIT(0); SBAR();
    ++s;
    PHASE(s, 0, false); SBAR();
    PHASE(s, 1, false);

    // epilogue: frag row = 4*(lane>>4)+r, col = lane&15
    size_t cz = strideC * blockIdx.z;
    const int rowb = bm * BM + wr * (16 * MR) + r4 * 4;
    const int colb = bn * BN + wc * (16 * NR) + r15;
#pragma unroll
    for (int m = 0; m < MR; ++m) {
#pragma unroll
        for (int r = 0; r < 4; ++r) {
            int row = rowb + m * 16 + r;
            size_t base = cz + (size_t)row * ldc + colb;
#pragma unroll
            for (int n = 0; n < NR; ++n) {
                float v = acc[m][n][r];
                size_t idx = base + n * 16;
                if (EPI == EPI_F32)       Cf[idx] = v;
                else if (EPI == EPI_BF16) Cb[idx] = f2bf(v);
                else if (EPI == EPI_RELU) Cb[idx] = f2bf(fmaxf(v, 0.f));
                else { float o = v + Res[idx]; Cf[idx] = o; Cb[idx] = f2bf(o); }
            }
        }
    }
#undef STAGE_PART
#undef PHASE
}

// ---------------------------------------------------------------------------
// Causal row softmax: scores fp32 [B][S][S] -> probs bf16 (zeros above diag)
// ---------------------------------------------------------------------------
__device__ __forceinline__ float wred_max(float v) {
#pragma unroll
    for (int off = 32; off; off >>= 1) v = fmaxf(v, __shfl_xor(v, off));
    return v;
}
__device__ __forceinline__ float wred_sum(float v) {
#pragma unroll
    for (int off = 32; off; off >>= 1) v += __shfl_xor(v, off);
    return v;
}

__global__ void bt_softmax(const float* __restrict__ scores, ushort* __restrict__ probs) {
    int row = blockIdx.x;
    int s   = row & (S_LEN - 1);
    const float* src = scores + (size_t)row * S_LEN;
    ushort*      dst = probs  + (size_t)row * S_LEN;
    int tid = threadIdx.x;
    int nvalid = s + 1;

    float vals[8];
    float mx = -1e30f;
#pragma unroll
    for (int j = 0; j < 8; ++j) {
        int t = tid + j * 256;
        float v = (t < nvalid) ? src[t] * 0.03125f : -1e30f;
        vals[j] = v;
        mx = fmaxf(mx, v);
    }
    __shared__ float red[4], red2[4];
    mx = wred_max(mx);
    if ((tid & 63) == 0) red[tid >> 6] = mx;
    __syncthreads();
    mx = fmaxf(fmaxf(red[0], red[1]), fmaxf(red[2], red[3]));

    float sum = 0.f, ps[8];
#pragma unroll
    for (int j = 0; j < 8; ++j) {
        float p = exp2f((vals[j] - mx) * 1.44269504f);
        ps[j] = p; sum += p;
    }
    sum = wred_sum(sum);
    if ((tid & 63) == 0) red2[tid >> 6] = sum;
    __syncthreads();
    sum = red2[0] + red2[1] + red2[2] + red2[3];
    float inv = 1.0f / sum;
#pragma unroll
    for (int j = 0; j < 8; ++j) {
        int t = tid + j * 256;
        dst[t] = (t < nvalid) ? f2bf(ps[j] * inv) : (ushort)0;
    }
}

// ---------------------------------------------------------------------------
// Last-token logits
// ---------------------------------------------------------------------------
__global__ void bt_logits(const float* __restrict__ h, const float* __restrict__ wout,
                          float* __restrict__ out) {
    __shared__ float hl[4][128];
    int tid = threadIdx.x;
    int d0 = blockIdx.y * 128;
    if (tid < 128) {
#pragma unroll
        for (int b = 0; b < 4; ++b)
            hl[b][tid] = h[((size_t)b * S_LEN + (S_LEN - 1)) * D_DIM + d0 + tid];
    }
    __syncthreads();
    int v = blockIdx.x * 256 + tid;
    float a0 = 0, a1 = 0, a2 = 0, a3 = 0;
    for (int j = 0; j < 128; ++j) {
        float w = wout[(size_t)(d0 + j) * V_DIM + v];
        a0 += hl[0][j] * w; a1 += hl[1][j] * w;
        a2 += hl[2][j] * w; a3 += hl[3][j] * w;
    }
    atomicAdd(out + v, a0);
    atomicAdd(out + V_DIM + v, a1);
    atomicAdd(out + 2 * V_DIM + v, a2);
    atomicAdd(out + 3 * V_DIM + v, a3);
}

// ---------------------------------------------------------------------------
extern "C" void kernel_launch(void* const* d_in, const int* in_sizes, int n_in,
                              void* d_out, int out_size, void* d_ws, size_t ws_size,
                              hipStream_t stream) {
    const int*   tokens = (const int*)d_in[0];
    const float* emb    = (const float*)d_in[1];
    const float* pe     = (const float*)d_in[2];
    const float* wout = (const float*)d_in[13];

    char* w = (char*)d_ws;
    size_t o = 0;
    auto take = [&](size_t sz) { char* p = w + o; o += (sz + 255) & ~(size_t)255; return p; };

    const size_t DD = (size_t)D_DIM * D_DIM * 2;
    const size_t DH = (size_t)D_DIM * H_DIM * 2;
    const size_t NROW = (size_t)B_SZ * S_LEN;

    ushort* wkvT[2]; ushort* woT[2]; ushort* w1T[2]; ushort* w2T[2];
    for (int l = 0; l < 2; ++l) {
        wkvT[l] = (ushort*)take(2 * DD);     // [2048][1024]: wk^T rows 0-1023, wv^T rows 1024-2047
        woT[l]  = (ushort*)take(DD);
        w1T[l]  = (ushort*)take(DH);         // [4096][1024]
        w2T[l]  = (ushort*)take(DH);         // [1024][4096]
    }

    float*  h0     = (float*)take(NROW * D_DIM * 4);
    float*  h1     = (float*)take(NROW * D_DIM * 4);
    ushort* hbf    = (ushort*)take(NROW * D_DIM * 2);
    ushort* hresbf = (ushort*)take(NROW * D_DIM * 2);
    ushort* xkv    = (ushort*)take(NROW * 2 * D_DIM * 2);     // [8192][2048]
    ushort* xvt    = (ushort*)take((size_t)D_DIM * NROW * 2); // [1024][8192]
    ushort* hattn  = (ushort*)take(NROW * D_DIM * 2);
    char*   G      = take((size_t)B_SZ * S_LEN * S_LEN * 4 + (size_t)B_SZ * S_LEN * S_LEN * 2);
    float*  scores = (float*)G;
    ushort* probs  = (ushort*)(G + (size_t)B_SZ * S_LEN * S_LEN * 4);
    ushort* tbf    = (ushort*)G;   // FFN hidden aliases scores (disjoint phases)

    // weight transposes (fp32 -> bf16, [R][C] -> [C][R])
    for (int l = 0; l < 2; ++l) {
        const float* wk = (const float*)d_in[3 + 5 * l + 0];
        const float* wv = (const float*)d_in[3 + 5 * l + 1];
        const float* wo = (const float*)d_in[3 + 5 * l + 2];
        const float* w1 = (const float*)d_in[3 + 5 * l + 3];
        const float* w2 = (const float*)d_in[3 + 5 * l + 4];
        bt_wtranspose<<<dim3(16, 16), 256, 0, stream>>>(wk, wkvT[l], 1024, 1024);
        bt_wtranspose<<<dim3(16, 16), 256, 0, stream>>>(wv, wkvT[l] + (size_t)D_DIM * D_DIM, 1024, 1024);
        bt_wtranspose<<<dim3(16, 16), 256, 0, stream>>>(wo, woT[l], 1024, 1024);
        bt_wtranspose<<<dim3(64, 16), 256, 0, stream>>>(w1, w1T[l], 1024, 4096);
        bt_wtranspose<<<dim3(16, 64), 256, 0, stream>>>(w2, w2T[l], 4096, 1024);
    }

    bt_embed<<<NROW, 256, 0, stream>>>(tokens, emb, pe, h0, hbf);

    auto layer = [&](int l) {
        // xkv = h @ [wk|wv] : M=8192, N=2048, K=1024; 256^2, grid 8x32 = 256
        bt_gemm<256, 256, 2, 4, EPI_BF16, false, false, 1><<<dim3(8, 32), 512, 0, stream>>>(
            hbf, wkvT[l], nullptr, xkv, nullptr, D_DIM, D_DIM, 2 * D_DIM, D_DIM, 0, 0, 0);
        // xvt = transpose(xkv[:, 1024:2048]) -> [1024][8192]
        bt_transpose<<<dim3(16, 128), 256, 0, stream>>>(xkv, xvt, (int)NROW, 2 * D_DIM, D_DIM);
        // scores = Q @ xk^T per batch (causal tiles), fp32; B = xkv cols 0-1023
        bt_gemm<256, 256, 2, 4, EPI_F32, true, false, 0><<<dim3(8, 8, B_SZ), 512, 0, stream>>>(
            hbf, xkv, scores, nullptr, nullptr, D_DIM, 2 * D_DIM, S_LEN, D_DIM,
            (size_t)S_LEN * D_DIM, (size_t)S_LEN * 2 * D_DIM, (size_t)S_LEN * S_LEN);
        bt_softmax<<<NROW, 256, 0, stream>>>(scores, probs);
        // h_attn = probs @ xv : B^T = xvt (per-batch col slice), KLIM; 256x128
        bt_gemm<256, 128, 4, 2, EPI_BF16, false, true, 0><<<dim3(8, 8, B_SZ), 512, 0, stream>>>(
            probs, xvt, nullptr, hattn, nullptr, S_LEN, (int)NROW, D_DIM, S_LEN,
            (size_t)S_LEN * S_LEN, (size_t)S_LEN, (size_t)S_LEN * D_DIM);
        // h_res = h + h_attn @ wo : 256x128, grid 8x32 = 256
        bt_gemm<256, 128, 4, 2, EPI_RES, false, false, 1><<<dim3(8, 32), 512, 0, stream>>>(
            hattn, woT[l], h1, hresbf, h0, D_DIM, D_DIM, D_DIM, D_DIM, 0, 0, 0);
        // t = relu(h_res @ w1) : 256^2, grid 16x32 = 512
        bt_gemm<256, 256, 2, 4, EPI_RELU, false, false, 1><<<dim3(16, 32), 512, 0, stream>>>(
            hresbf, w1T[l], nullptr, tbf, nullptr, D_DIM, D_DIM, H_DIM, D_DIM, 0, 0, 0);
        // h = h_res + t @ w2 : K=4096; 256x128, grid 8x32 = 256
        bt_gemm<256, 128, 4, 2, EPI_RES, false, false, 1><<<dim3(8, 32), 512, 0, stream>>>(
            tbf, w2T[l], h0, hbf, h1, H_DIM, H_DIM, D_DIM, H_DIM, 0, 0, 0);
    };
    layer(0);
    layer(1);

    hipMemsetAsync(d_out, 0, (size_t)B_SZ * V_DIM * sizeof(float), stream);
    bt_logits<<<dim3(V_DIM / 256, D_DIM / 128), 256, 0, stream>>>(h0, wout, (float*)d_out);
}